// Round 8
// baseline (7761.169 us; speedup 1.0000x reference)
//
#include <hip/hip_runtime.h>
#include <stdint.h>

#define NB    64
#define NN    131072
#define NPTS  1024
#define TPB   1024                 // 16 waves (R6-proven geometry)
#define WPB   4                    // workgroups per batch
#define NWAVE (TPB / 64)
#define CHUNK (NN / WPB)           // 32768 points per wg
#define PPT   (CHUNK / TPB)        // 32 points per thread
#define RPTS  20                   // register-resident points/thread
#define LPTS  12                   // LDS-resident points/thread
#define RPAIR (RPTS / 2)
#define LPAIR (LPTS / 2)

typedef float v2f __attribute__((ext_vector_type(2)));
typedef unsigned long long u64;

static __device__ __forceinline__ v2f vmin2(v2f a, v2f b) {
#if __has_builtin(__builtin_elementwise_min)
    return __builtin_elementwise_min(a, b);
#else
    v2f r; r.x = fminf(a.x, b.x); r.y = fminf(a.y, b.y); return r;
#endif
}

// ---------------- inter-wg protocol: relaxed + stamped + COLD slots ----------
// HW LESSONS (R4/R5): RELAXED atomics only (acquire/release at agent scope =
// cache-maintenance storm, 118x); never reuse a global spin address within a
// launch (per-round-unique slots -> every poll target is a cold line).
// NEW (R8): only wave 0 polls global slots (agent-scope loads go to the
// coherence point; 16 waves x 64 lanes polling = MALL congestion); waves 1..15
// poll a stamped LDS broadcast word instead (workgroup scope, ds_read).
// PAYLOAD=1: winner publishes coords too -> no serial P[widx] reload.
//   slot (k, rank) = 4 u64: w0=x<<32|k  w1=y<<32|k  w2=z<<32|k
//                           w3=dist<<32|(NN-1-idx)<<10|k
//   w3 u64-max == (max dist, then min idx) == jnp.argmax tie-break (same-k
//   stamps cancel). Slots memset to 0 each launch: stamp 0 never matches, and
//   the 0xAA poison (stamp 682) can never false-match at k=682.
// PAYLOAD=0 fallback (small ws): 1 u64 [dist|~idx] per slot, nonzero = flag;
//   wave0 reloads P[widx] once and broadcasts via LDS.

template <bool PAYLOAD>
__global__ __launch_bounds__(TPB)
__attribute__((amdgpu_waves_per_eu(4, 4)))
void fps_kernel(
    const float* __restrict__ pos,
    const int*   __restrict__ start_p,
    int*         __restrict__ out,
    u64*         __restrict__ slots)
{
#pragma clang fp contract(off)
    const int wg   = blockIdx.x;
    const int xcd  = wg & 7;            // heuristic: keep a batch's 4 wgs on one XCD
    const int sl   = wg >> 3;
    const int b    = xcd * 8 + (sl >> 2);
    const int r    = sl & 3;
    const int t    = threadIdx.x;
    const int lane = t & 63;
    const int wv   = t >> 6;

    const float* __restrict__ P  = pos + (size_t)b * NN * 3;
    const float* __restrict__ Pc = P + (size_t)r * CHUNK * 3;
    u64* __restrict__ bslots = slots +
        (PAYLOAD ? (size_t)b * NPTS * WPB * 4 : (size_t)b * NPTS * WPB);

    // pair-packed LDS: coords of points (2l, 2l+1) adjacent -> ds_read_b64
    __shared__ float lx[LPAIR * TPB * 2];
    __shared__ float ly[LPAIR * TPB * 2];
    __shared__ float lz[LPAIR * TPB * 2];   // 147456 B
    __shared__ u64   wred[2][NWAVE];        // banked by k&1 (single-barrier loop)
    __shared__ u64   bc[2][3];              // stamped winner-coord broadcast

    // ---- one-time staging: j<RPTS -> regs, rest -> LDS (own-thread only) ----
    v2f rx[RPAIR], ry[RPAIR], rz[RPAIR];
#pragma unroll
    for (int p = 0; p < RPAIR; ++p) {
        const float* a = Pc + (size_t)(t + (2 * p) * TPB) * 3;
        const float* c = a + (size_t)TPB * 3;
        rx[p] = (v2f){a[0], c[0]};
        ry[p] = (v2f){a[1], c[1]};
        rz[p] = (v2f){a[2], c[2]};
    }
#pragma unroll
    for (int l = 0; l < LPAIR; ++l) {
        const float* a = Pc + (size_t)(t + (RPTS + 2 * l) * TPB) * 3;
        const float* c = a + (size_t)TPB * 3;
        const int idx = (l * TPB + t) * 2;
        lx[idx] = a[0]; lx[idx + 1] = c[0];
        ly[idx] = a[1]; ly[idx + 1] = c[1];
        lz[idx] = a[2]; lz[idx + 1] = c[2];
    }
    if (t < 6) ((u64*)bc)[t] = 0;          // stamp 0 never matches k>=1

    const int start = start_p[0];
    float sx = P[(size_t)start * 3 + 0];
    float sy = P[(size_t)start * 3 + 1];
    float sz = P[(size_t)start * 3 + 2];
    if (r == 0 && t == 0) out[(size_t)b * NPTS] = start;

    v2f dist[PPT / 2];
#pragma unroll
    for (int p = 0; p < PPT / 2; ++p)
        dist[p] = (v2f){__builtin_inff(), __builtin_inff()};

    __syncthreads();   // bc zero-init visible to all waves

    const int gbase = r * CHUNK;

    for (int k = 1; k < NPTS; ++k) {
        const int bank = k & 1;
        const v2f s0 = (v2f){sx, sx}, s1 = (v2f){sy, sy}, s2 = (v2f){sz, sz};
        float best = -1.0f;
        int   bi   = 0;

        // exact per-op rounding: (dx*dx + dy*dy) + dz*dz, contract off;
        // ascending j preserves first-occurrence argmax tie-break
#define PAIR_STEP(DP, PX, PY, PZ, I0)                                    \
        {                                                                \
            v2f dx = (PX) - s0, dy = (PY) - s1, dz = (PZ) - s2;          \
            v2f d  = (dx * dx + dy * dy) + dz * dz;                      \
            v2f nd = vmin2(dist[DP], d);                                 \
            dist[DP] = nd;                                               \
            if (nd.x > best) { best = nd.x; bi = (I0); }                 \
            if (nd.y > best) { best = nd.y; bi = (I0) + TPB; }           \
        }

#pragma unroll
        for (int p = 0; p < RPAIR; ++p)
            PAIR_STEP(p, rx[p], ry[p], rz[p], gbase + t + (2 * p) * TPB);
#pragma unroll
        for (int l = 0; l < LPAIR; ++l) {
            const int idx = (l * TPB + t) * 2;
            v2f px = *reinterpret_cast<const v2f*>(&lx[idx]);   // ds_read_b64
            v2f py = *reinterpret_cast<const v2f*>(&ly[idx]);
            v2f pz = *reinterpret_cast<const v2f*>(&lz[idx]);
            PAIR_STEP(RPAIR + l, px, py, pz, gbase + t + (RPTS + 2 * l) * TPB);
        }
#undef PAIR_STEP

        const u64 pk0 = ((u64)__float_as_uint(best) << 32) | (unsigned)~bi;

        // 64-lane wave max-reduce
        u64 pk = pk0;
#pragma unroll
        for (int o = 32; o >= 1; o >>= 1) {
            u64 q = __shfl_xor(pk, o, 64);
            if (q > pk) pk = q;
        }
        if (lane == 0) wred[bank][wv] = pk;
        __syncthreads();

        // every wave reduces the 16 wave-partials (winner must self-identify)
        u64 v = wred[bank][lane & (NWAVE - 1)];
#pragma unroll
        for (int o = 1; o < NWAVE; o <<= 1) {
            u64 q = __shfl_xor(v, o, 64);
            if (q > v) v = q;
        }

        if (PAYLOAD) {
            // unique block winner (key embeds index) publishes coords + key
            if (pk0 == v) {
                const int j = (bi - gbase - t) >> 10;   // TPB = 1024
                float wx, wy, wz;
                if (j < RPTS) {
                    wx = 0.f; wy = 0.f; wz = 0.f;
#pragma unroll
                    for (int p = 0; p < RPAIR; ++p) {
                        if (j == 2 * p)     { wx = rx[p].x; wy = ry[p].x; wz = rz[p].x; }
                        if (j == 2 * p + 1) { wx = rx[p].y; wy = ry[p].y; wz = rz[p].y; }
                    }
                } else {
                    const int jj  = j - RPTS;
                    const int idx = ((jj >> 1) * TPB + t) * 2 + (jj & 1);
                    wx = lx[idx]; wy = ly[idx]; wz = lz[idx];
                }
                u64* sb = bslots + ((size_t)k * WPB + r) * 4;
                const u64 kk = (u64)(unsigned)k;
                __hip_atomic_store(sb + 0, ((u64)__float_as_uint(wx) << 32) | kk,
                                   __ATOMIC_RELAXED, __HIP_MEMORY_SCOPE_AGENT);
                __hip_atomic_store(sb + 1, ((u64)__float_as_uint(wy) << 32) | kk,
                                   __ATOMIC_RELAXED, __HIP_MEMORY_SCOPE_AGENT);
                __hip_atomic_store(sb + 2, ((u64)__float_as_uint(wz) << 32) | kk,
                                   __ATOMIC_RELAXED, __HIP_MEMORY_SCOPE_AGENT);
                const u64 w3 = (pk0 & 0xFFFFFFFF00000000ull) |
                               ((u64)(unsigned)(NN - 1 - bi) << 10) | kk;
                __hip_atomic_store(sb + 3, w3,
                                   __ATOMIC_RELAXED, __HIP_MEMORY_SCOPE_AGENT);
            }
        } else {
            if (t == 0)
                __hip_atomic_store(&bslots[(size_t)k * WPB + r], v,
                                   __ATOMIC_RELAXED, __HIP_MEMORY_SCOPE_AGENT);
        }

        if (wv == 0) {
            // ---- wave 0 only: global spin + cross-rank combine + LDS bcast ----
            if (PAYLOAD) {
                const u64* sp = bslots + ((size_t)k * WPB + (lane & 3)) * 4;
                u64 w3;
                for (;;) {
                    w3 = __hip_atomic_load(sp + 3, __ATOMIC_RELAXED, __HIP_MEMORY_SCOPE_AGENT);
                    if ((unsigned)(w3 & 1023ull) == (unsigned)k) break;
                    __builtin_amdgcn_s_sleep(1);
                }
                u64 w0, w1, w2;
                for (;;) {
                    w0 = __hip_atomic_load(sp + 0, __ATOMIC_RELAXED, __HIP_MEMORY_SCOPE_AGENT);
                    if ((unsigned)w0 == (unsigned)k) break;
                }
                for (;;) {
                    w1 = __hip_atomic_load(sp + 1, __ATOMIC_RELAXED, __HIP_MEMORY_SCOPE_AGENT);
                    if ((unsigned)w1 == (unsigned)k) break;
                }
                for (;;) {
                    w2 = __hip_atomic_load(sp + 2, __ATOMIC_RELAXED, __HIP_MEMORY_SCOPE_AGENT);
                    if ((unsigned)w2 == (unsigned)k) break;
                }
#pragma unroll
                for (int o = 1; o <= 2; o <<= 1) {
                    u64 q3 = __shfl_xor(w3, o, 64);
                    u64 q0 = __shfl_xor(w0, o, 64);
                    u64 q1 = __shfl_xor(w1, o, 64);
                    u64 q2 = __shfl_xor(w2, o, 64);
                    if (q3 > w3) { w3 = q3; w0 = q0; w1 = q1; w2 = q2; }
                }
                if (lane == 0) {
                    if (r == 0)
                        out[(size_t)b * NPTS + k] =
                            NN - 1 - (int)((w3 >> 10) & 0x1FFFFull);
                    __hip_atomic_store(&bc[bank][0], w0, __ATOMIC_RELAXED, __HIP_MEMORY_SCOPE_WORKGROUP);
                    __hip_atomic_store(&bc[bank][1], w1, __ATOMIC_RELAXED, __HIP_MEMORY_SCOPE_WORKGROUP);
                    __hip_atomic_store(&bc[bank][2], w2, __ATOMIC_RELAXED, __HIP_MEMORY_SCOPE_WORKGROUP);
                }
                sx = __uint_as_float((unsigned)(w0 >> 32));
                sy = __uint_as_float((unsigned)(w1 >> 32));
                sz = __uint_as_float((unsigned)(w2 >> 32));
            } else {
                const u64* sp = &bslots[(size_t)k * WPB + (lane & 3)];
                u64 g;
                for (;;) {
                    g = __hip_atomic_load(sp, __ATOMIC_RELAXED, __HIP_MEMORY_SCOPE_AGENT);
                    if (g) break;
                    __builtin_amdgcn_s_sleep(1);
                }
#pragma unroll
                for (int o = 1; o <= 2; o <<= 1) {
                    u64 q = __shfl_xor(g, o, 64);
                    if (q > g) g = q;
                }
                const int widx = (int)~(unsigned)g;
                const float nx = P[(size_t)widx * 3 + 0];   // uniform: 1 txn, wave0 only
                const float ny = P[(size_t)widx * 3 + 1];
                const float nz = P[(size_t)widx * 3 + 2];
                if (lane == 0) {
                    if (r == 0) out[(size_t)b * NPTS + k] = widx;
                    const u64 kk = (u64)(unsigned)k;
                    __hip_atomic_store(&bc[bank][0], ((u64)__float_as_uint(nx) << 32) | kk,
                                       __ATOMIC_RELAXED, __HIP_MEMORY_SCOPE_WORKGROUP);
                    __hip_atomic_store(&bc[bank][1], ((u64)__float_as_uint(ny) << 32) | kk,
                                       __ATOMIC_RELAXED, __HIP_MEMORY_SCOPE_WORKGROUP);
                    __hip_atomic_store(&bc[bank][2], ((u64)__float_as_uint(nz) << 32) | kk,
                                       __ATOMIC_RELAXED, __HIP_MEMORY_SCOPE_WORKGROUP);
                }
                sx = nx; sy = ny; sz = nz;
            }
        } else {
            // ---- waves 1..15: poll cheap stamped LDS broadcast (no MALL) ----
            u64 c0, c1, c2;
            for (;;) {
                c0 = __hip_atomic_load(&bc[bank][0], __ATOMIC_RELAXED, __HIP_MEMORY_SCOPE_WORKGROUP);
                if ((unsigned)c0 == (unsigned)k) break;
                __builtin_amdgcn_s_sleep(1);
            }
            for (;;) {
                c1 = __hip_atomic_load(&bc[bank][1], __ATOMIC_RELAXED, __HIP_MEMORY_SCOPE_WORKGROUP);
                if ((unsigned)c1 == (unsigned)k) break;
            }
            for (;;) {
                c2 = __hip_atomic_load(&bc[bank][2], __ATOMIC_RELAXED, __HIP_MEMORY_SCOPE_WORKGROUP);
                if ((unsigned)c2 == (unsigned)k) break;
            }
            sx = __uint_as_float((unsigned)(c0 >> 32));
            sy = __uint_as_float((unsigned)(c1 >> 32));
            sz = __uint_as_float((unsigned)(c2 >> 32));
        }
        // bc[bank] reuse at k+2 is safe: wave0 reaches that write only after
        // two barriers, each requiring all waves to have finished polling bc[k].
    }
}

extern "C" void kernel_launch(void* const* d_in, const int* in_sizes, int n_in,
                              void* d_out, int out_size, void* d_ws, size_t ws_size,
                              hipStream_t stream)
{
    const float* pos     = (const float*)d_in[0];
    const int*   start_p = (const int*)d_in[1];
    int*         out     = (int*)d_out;
    u64*         slots   = (u64*)d_ws;

    const size_t needP = (size_t)NB * NPTS * WPB * 4 * sizeof(u64);  // 8 MB
    const size_t need1 = (size_t)NB * NPTS * WPB * sizeof(u64);      // 2 MB

    void* args[] = { (void*)&pos, (void*)&start_p, (void*)&out, (void*)&slots };

    if (ws_size >= needP) {
        hipMemsetAsync(d_ws, 0, needP, stream);
        hipError_t e = hipLaunchCooperativeKernel(
            (const void*)fps_kernel<true>, dim3(NB * WPB), dim3(TPB),
            args, 0, stream);
        if (e != hipSuccess)
            fps_kernel<true><<<dim3(NB * WPB), dim3(TPB), 0, stream>>>(
                pos, start_p, out, slots);
    } else {
        hipMemsetAsync(d_ws, 0, need1, stream);
        hipError_t e = hipLaunchCooperativeKernel(
            (const void*)fps_kernel<false>, dim3(NB * WPB), dim3(TPB),
            args, 0, stream);
        if (e != hipSuccess)
            fps_kernel<false><<<dim3(NB * WPB), dim3(TPB), 0, stream>>>(
                pos, start_p, out, slots);
    }
}